// Round 7
// baseline (16316.626 us; speedup 1.0000x reference)
//
#include <hip/hip_runtime.h>
#include <math.h>

#define NI  2
#define BB  32
#define DD  512
#define HWX 324
#define LL  648
#define MM  648
#define KX  128

#define TEMPF  30.0f
#define NEPSF  1e-5f
#define L2EPSF 1e-12f
#define DHWF   165888.0f
#define NSDF   0.011048543456039806f

// ---------- exact numpy pairwise-sum building blocks (fp32) ------------------
// n multiple of 8, 8 <= n <= 128: unrolled-by-8 with 8 accumulators
__device__ __forceinline__ float pw_le128(const float* a, int n) {
  float r0 = a[0], r1 = a[1], r2 = a[2], r3 = a[3];
  float r4 = a[4], r5 = a[5], r6 = a[6], r7 = a[7];
  for (int i = 8; i < n; i += 8) {
    r0 += a[i];     r1 += a[i + 1]; r2 += a[i + 2]; r3 += a[i + 3];
    r4 += a[i + 4]; r5 += a[i + 5]; r6 += a[i + 6]; r7 += a[i + 7];
  }
  return ((r0 + r1) + (r2 + r3)) + ((r4 + r5) + (r6 + r7));
}
// numpy pairwise for n=648: 648->320+328; 320->160+160; 328->160+168;
// 160->80+80; 168->80+88
__device__ __forceinline__ float pw648(const float* a) {
  float l = (pw_le128(a, 80) + pw_le128(a + 80, 80)) +
            (pw_le128(a + 160, 80) + pw_le128(a + 240, 80));        // pw320
  float r = (pw_le128(a + 320, 80) + pw_le128(a + 400, 80)) +
            (pw_le128(a + 480, 80) + pw_le128(a + 560, 88));        // pw328
  return l + r;
}

// ---------- input staging (exact fp32 copies) --------------------------------
__global__ void k_flat(const float* __restrict__ src, float* __restrict__ x) {
  size_t idx = (size_t)blockIdx.x * 256 + threadIdx.x;
  int r = (int)(idx >> 9), d = (int)(idx & 511);
  int l = r >> 5, b = r & 31;
  int i = l / HWX, s = l % HWX;
  x[idx] = src[((size_t)(i * BB + b) * DD + d) * HWX + s];
}

__global__ void k_addpe(const float* __restrict__ pe, float* __restrict__ x) {
  size_t idx = (size_t)blockIdx.x * 256 + threadIdx.x;
  int r = (int)(idx >> 9), d = (int)(idx & 511);
  int l = r >> 5, b = r & 31;
  int i = l / HWX, s = l % HWX;
  float t = __fmul_rn(pe[((size_t)(i * BB + b) * DD + d) * HWX + s], 0.001f);
  x[idx] = __fadd_rn(x[idx], t);
}

__global__ void k_pos(const float* __restrict__ pos, float* __restrict__ ps) {
  int idx = blockIdx.x * 256 + threadIdx.x;  // 20736
  int l = idx >> 5, b = idx & 31;
  int j = l / HWX, s = l % HWX;
  ps[idx] = pos[((size_t)(j * BB + b)) * HWX + s];
}

__global__ void k_memp(const float* __restrict__ mem, const float* __restrict__ ps,
                       float* __restrict__ memp) {
  size_t idx = (size_t)blockIdx.x * 256 + threadIdx.x;
  memp[idx] = __fmul_rn(mem[idx], ps[idx >> 9]);
}

__global__ void k_wt(const float* __restrict__ W, float* __restrict__ Wt) {
  int idx = blockIdx.x * 256 + threadIdx.x;  // 65536: dst [d][k]
  int k = idx & 127, d = idx >> 7;
  Wt[idx] = W[(size_t)k * DD + d];
}

// ---------- projection + bias + l2norm (numpy-order fp32) --------------------
// row r = l*32+b; out[r,k] = (x_r . W_k  [k-seq fmaf] + bk) / max(||.||, 1e-12)
__global__ __launch_bounds__(128) void k_proj(const float* __restrict__ A,
                                              const float* __restrict__ Wt,
                                              const float* __restrict__ bias,
                                              float* __restrict__ out) {
  int r = blockIdx.x;
  int t = threadIdx.x;  // k
  __shared__ float xs[DD];
  __shared__ float sq[KX];
  __shared__ float pr[8];
  __shared__ float nsh;
  const float* arow = A + (size_t)r * DD;
  for (int d = t; d < DD; d += 128) xs[d] = arow[d];
  __syncthreads();
  float acc = 0.0f;
  for (int d = 0; d < DD; d++) acc = fmaf(xs[d], Wt[(size_t)d * KX + t], acc);
  float val = __fadd_rn(acc, bias[t]);
  sq[t] = __fmul_rn(val, val);
  __syncthreads();
  if (t < 8) {  // numpy unroll-8 partials, blocks ascending
    float rr = sq[t];
    for (int blk = 1; blk < 16; blk++) rr += sq[blk * 8 + t];
    pr[t] = rr;
  }
  __syncthreads();
  if (t == 0) {
    float ss = ((pr[0] + pr[1]) + (pr[2] + pr[3])) + ((pr[4] + pr[5]) + (pr[6] + pr[7]));
    float n = __fsqrt_rn(ss);
    nsh = fmaxf(n, L2EPSF);
  }
  __syncthreads();
  out[(size_t)r * KX + t] = __fdiv_rn(val, nsh);
}

// wkt[(b*128+k)*648+s] = wk[(s*32+b)*128+k]
__global__ void k_wkt(const float* __restrict__ wk, float* __restrict__ wkt) {
  int idx = blockIdx.x * 256 + threadIdx.x;  // 2,654,208
  int s = idx % MM;
  int k = (idx / MM) & 127;
  int b = idx / (MM * KX);
  wkt[idx] = wk[((size_t)s * BB + b) * KX + k];
}

// ---------- scores: sc[(b*648+q)*648+s] = 30 * (wq_qb . wk_sb) [k-seq fmaf] --
__global__ __launch_bounds__(256) void k_score(const float* __restrict__ wq,
                                               const float* __restrict__ wkt,
                                               float* __restrict__ sc) {
  int row = blockIdx.x;  // b*648+q
  int b = row / LL, q = row % LL;
  __shared__ float qs[KX];
  int t = threadIdx.x;
  if (t < KX) qs[t] = wq[((size_t)q * BB + b) * KX + t];
  __syncthreads();
  float* srow = sc + (size_t)row * MM;
  const float* kb = wkt + (size_t)b * KX * MM;
  for (int s = t; s < MM; s += 256) {
    float acc = 0.0f;
    for (int k = 0; k < KX; k++) acc = fmaf(qs[k], kb[(size_t)k * MM + s], acc);
    srow[s] = __fmul_rn(acc, TEMPF);
  }
}

// ---------- softmax row: max-sub, CR exp, numpy-pairwise-648 sum, division ---
__global__ __launch_bounds__(256) void k_sm(float* __restrict__ sc) {
  int row = blockIdx.x;
  float* p = sc + (size_t)row * MM;
  int t = threadIdx.x;
  __shared__ float red[256];
  __shared__ float es[MM];
  __shared__ float ssum;
  float v0 = p[t], v1 = p[t + 256];
  bool h2 = t < (MM - 512);
  float v2 = h2 ? p[t + 512] : -3.0e38f;
  red[t] = fmaxf(fmaxf(v0, v1), v2);
  __syncthreads();
  for (int off = 128; off; off >>= 1) {
    if (t < off) red[t] = fmaxf(red[t], red[t + off]);
    __syncthreads();
  }
  float mx = red[0];
  float e0 = (float)exp((double)__fsub_rn(v0, mx));
  float e1 = (float)exp((double)__fsub_rn(v1, mx));
  float e2 = h2 ? (float)exp((double)__fsub_rn(v2, mx)) : 0.0f;
  es[t] = e0; es[t + 256] = e1;
  if (h2) es[t + 512] = e2;
  __syncthreads();
  if (t == 0) ssum = pw648(es);
  __syncthreads();
  float s = ssum;
  p[t] = __fdiv_rn(e0, s);
  p[t + 256] = __fdiv_rn(e1, s);
  if (h2) p[t + 512] = __fdiv_rn(e2, s);
}

// ---------- apply: out[q,b,d] = sum_s aff*V  [s-seq fmaf], 4 q per block -----
__global__ __launch_bounds__(512) void k_apply(const float* __restrict__ sc,
                                               const float* __restrict__ V,
                                               float* __restrict__ out) {
  int q0 = blockIdx.x * 4;
  int b = blockIdx.y;
  int t = threadIdx.x;  // d
  __shared__ float affs[4 * MM];
  const float* base = sc + ((size_t)b * LL + q0) * MM;
  for (int j = t; j < 4 * MM; j += 512) affs[j] = base[j];
  __syncthreads();
  float a0 = 0.f, a1 = 0.f, a2 = 0.f, a3 = 0.f;
  for (int s = 0; s < MM; s++) {
    float vv = V[((size_t)s * BB + b) * DD + t];
    a0 = fmaf(affs[s], vv, a0);
    a1 = fmaf(affs[MM + s], vv, a1);
    a2 = fmaf(affs[2 * MM + s], vv, a2);
    a3 = fmaf(affs[3 * MM + s], vv, a3);
  }
  out[((size_t)(q0 + 0) * BB + b) * DD + t] = a0;
  out[((size_t)(q0 + 1) * BB + b) * DD + t] = a1;
  out[((size_t)(q0 + 2) * BB + b) * DD + t] = a2;
  out[((size_t)(q0 + 3) * BB + b) * DD + t] = a3;
}

// ---------- mask[q*32+b] = sum_s aff*ps  [s-seq fmaf] ------------------------
__global__ void k_mask(const float* __restrict__ sc, const float* __restrict__ ps,
                       float* __restrict__ msk) {
  int tid = blockIdx.x * 256 + threadIdx.x;
  if (tid >= BB * LL) return;
  int b = tid / LL, q = tid % LL;
  const float* arow = sc + (size_t)tid * MM;
  float acc = 0.0f;
  for (int s = 0; s < MM; s++) acc = fmaf(arow[s], ps[s * BB + b], acc);
  msk[q * BB + b] = acc;
}

// ---------- instance-norm stage A: per (g,s) numpy-pw512 of squares ----------
// MODE 1: y=x+ao -> tU | MODE 2: u=x*mk,v=x+ao -> tU,tV | MODE 3: w -> tU
template <int MODE>
__global__ __launch_bounds__(128) void k_na(const float* __restrict__ x,
                                            const float* __restrict__ ao,
                                            const float* __restrict__ msk,
                                            const float* __restrict__ scu,
                                            const float* __restrict__ scv,
                                            float* __restrict__ tU,
                                            float* __restrict__ tV) {
  int s = blockIdx.x;       // 0..323
  int g = blockIdx.y;       // i*32+b
  int i = g >> 5, b = g & 31;
  int l = i * HWX + s;
  size_t base = ((size_t)l * BB + b) * DD;
  int t = threadIdx.x;
  __shared__ float squ[DD];
  __shared__ float sqv[DD];
  __shared__ float pru[32];
  __shared__ float prv[32];
  float mk = 0.f, su = 0.f, sv = 0.f;
  if (MODE >= 2) mk = msk[l * BB + b];
  if (MODE == 3) { su = scu[g]; sv = scv[g]; }
  for (int d = t; d < DD; d += 128) {
    float xx = x[base + d];
    if (MODE == 1) {
      float y = __fadd_rn(xx, ao[base + d]);
      squ[d] = __fmul_rn(y, y);
    } else if (MODE == 2) {
      float u = __fmul_rn(xx, mk);
      float v = __fadd_rn(xx, ao[base + d]);
      squ[d] = __fmul_rn(u, u);
      sqv[d] = __fmul_rn(v, v);
    } else {
      float u = __fmul_rn(xx, mk);
      float v = __fadd_rn(xx, ao[base + d]);
      float t2 = __fmul_rn(u, su);
      float t4 = __fmul_rn(v, sv);
      float w = __fadd_rn(t2, t4);
      squ[d] = __fmul_rn(w, w);
    }
  }
  __syncthreads();
  if (t < 32) {  // numpy pw128 partials per 128-chunk, blocks ascending
    int c = t >> 3, jj = t & 7, b0 = c * 128;
    float r = squ[b0 + jj];
    for (int blk = 1; blk < 16; blk++) r += squ[b0 + blk * 8 + jj];
    pru[t] = r;
    if (MODE == 2) {
      float r2 = sqv[b0 + jj];
      for (int blk = 1; blk < 16; blk++) r2 += sqv[b0 + blk * 8 + jj];
      prv[t] = r2;
    }
  }
  __syncthreads();
  if (t == 0) {
    float cc[4];
    for (int c = 0; c < 4; c++)
      cc[c] = ((pru[c * 8] + pru[c * 8 + 1]) + (pru[c * 8 + 2] + pru[c * 8 + 3])) +
              ((pru[c * 8 + 4] + pru[c * 8 + 5]) + (pru[c * 8 + 6] + pru[c * 8 + 7]));
    tU[g * HWX + s] = (cc[0] + cc[1]) + (cc[2] + cc[3]);
    if (MODE == 2) {
      for (int c = 0; c < 4; c++)
        cc[c] = ((prv[c * 8] + prv[c * 8 + 1]) + (prv[c * 8 + 2] + prv[c * 8 + 3])) +
                ((prv[c * 8 + 4] + prv[c * 8 + 5]) + (prv[c * 8 + 6] + prv[c * 8 + 7]));
      tV[g * HWX + s] = (cc[0] + cc[1]) + (cc[2] + cc[3]);
    }
  }
}

// stage B: sequential s-accumulation (numpy outer-axis order) + scale
__global__ void k_fin1(const float* __restrict__ tU, float* __restrict__ scl) {
  int g = threadIdx.x;  // 64
  float ss = 0.0f;
  for (int s = 0; s < HWX; s++) ss += tU[g * HWX + s];
  scl[g] = __fmul_rn(NSDF, __fsqrt_rn(__fdiv_rn(DHWF, __fadd_rn(ss, NEPSF))));
}

__global__ void k_fin2(const float* __restrict__ tU, const float* __restrict__ tV,
                       float* __restrict__ scu, float* __restrict__ scv) {
  int g = threadIdx.x;
  float su = 0.0f, sv = 0.0f;
  for (int s = 0; s < HWX; s++) { su += tU[g * HWX + s]; sv += tV[g * HWX + s]; }
  scu[g] = __fmul_rn(NSDF, __fsqrt_rn(__fdiv_rn(DHWF, __fadd_rn(su, NEPSF))));
  scv[g] = __fmul_rn(NSDF, __fsqrt_rn(__fdiv_rn(DHWF, __fadd_rn(sv, NEPSF))));
}

__global__ void k_a1(float* __restrict__ x, const float* __restrict__ ao,
                     const float* __restrict__ scl) {
  size_t idx = (size_t)blockIdx.x * 256 + threadIdx.x;
  int r = (int)(idx >> 9);
  int l = r >> 5, b = r & 31;
  int g = (l / HWX) * BB + b;
  x[idx] = __fmul_rn(__fadd_rn(x[idx], ao[idx]), scl[g]);
}

__global__ void k_a2(float* __restrict__ x, const float* __restrict__ ao,
                     const float* __restrict__ msk, const float* __restrict__ scu,
                     const float* __restrict__ scv, const float* __restrict__ scw) {
  size_t idx = (size_t)blockIdx.x * 256 + threadIdx.x;
  int r = (int)(idx >> 9);
  int l = r >> 5, b = r & 31;
  int g = (l / HWX) * BB + b;
  float mk = msk[l * BB + b];
  float xx = x[idx];
  float u = __fmul_rn(xx, mk);
  float v = __fadd_rn(xx, ao[idx]);
  float t2 = __fmul_rn(u, scu[g]);
  float t4 = __fmul_rn(v, scv[g]);
  float w = __fadd_rn(t2, t4);
  x[idx] = __fmul_rn(w, scw[g]);
}

// ---------- outputs ----------------------------------------------------------
__global__ void k_o0(const float* __restrict__ x, float* __restrict__ out) {
  size_t idx = (size_t)blockIdx.x * 256 + threadIdx.x;
  out[idx] = x[idx];
}

__global__ void k_o1(const float* __restrict__ x, float* __restrict__ out1) {
  size_t idx = (size_t)blockIdx.x * 256 + threadIdx.x;
  int s = (int)(idx % HWX);
  int d = (int)((idx / HWX) & 511);
  int ib = (int)(idx / ((size_t)HWX * DD));
  int i = ib >> 5, b = ib & 31;
  int l = i * HWX + s;
  out1[idx] = x[((size_t)l * BB + b) * DD + d];
}

// ---------------------------------------------------------------------------
extern "C" void kernel_launch(void* const* d_in, const int* in_sizes, int n_in,
                              void* d_out, int out_size, void* d_ws, size_t ws_size,
                              hipStream_t stream) {
  const float* tgt = (const float*)d_in[0];
  const float* pe  = (const float*)d_in[1];
  const float* mem = (const float*)d_in[2];
  const float* pos = (const float*)d_in[3];
  const float* Wks = (const float*)d_in[4];
  const float* bks = (const float*)d_in[5];
  const float* Wkc = (const float*)d_in[6];
  const float* bkc = (const float*)d_in[7];
  float* out = (float*)d_out;

  // 56,118,528 floats = 224,474,112 bytes (< proven 239.5 MB budget)
  if (ws_size < (size_t)224474112) return;
  float* f = (float*)d_ws;
  float* x    = f;                  // 10,616,832  [l,b,d]
  float* ao   = f + 10616832;       // 10,616,832
  float* memp = f + 21233664;       // 10,616,832
  float* wq   = f + 31850496;       //  2,654,208  [l,b,k]
  float* wkm  = f + 34504704;       //  2,654,208
  float* wktS = f + 37158912;       //  2,654,208  [b,k,s]
  float* wktC = f + 39813120;       //  2,654,208
  float* sc   = f + 42467328;       // 13,436,928  [b,q,s]
  float* msk  = f + 55904256;       //     20,736  [q,b]
  float* ps   = f + 55924992;       //     20,736  [l,b]
  float* tU   = f + 55945728;       //     20,736
  float* tV   = f + 55966464;       //     20,736
  float* scl  = f + 55987200;       //        256
  float* scu  = scl + 64;
  float* scv  = scl + 128;
  float* scw  = scl + 192;
  float* Wst  = f + 55987456;       //     65,536  [d,k]
  float* Wct  = f + 56052992;       //     65,536

  k_wt<<<256, 256, 0, stream>>>(Wks, Wst);
  k_wt<<<256, 256, 0, stream>>>(Wkc, Wct);
  k_flat<<<41472, 256, 0, stream>>>(tgt, x);
  k_pos<<<81, 256, 0, stream>>>(pos, ps);
  k_memp<<<41472, 256, 0, stream>>>(mem, ps, memp);
  // loop-invariant cross keys from memory
  k_proj<<<20736, 128, 0, stream>>>(mem, Wct, bkc, wkm);
  k_wkt<<<10368, 256, 0, stream>>>(wkm, wktC);

  dim3 apg(162, 32);
  dim3 nag(324, 64);
  for (int l = 0; l < 6; l++) {
    k_addpe<<<41472, 256, 0, stream>>>(pe, x);
    // --- self-attention (q=k=v=x) ---
    k_proj<<<20736, 128, 0, stream>>>(x, Wst, bks, wq);
    k_wkt<<<10368, 256, 0, stream>>>(wq, wktS);
    k_score<<<20736, 256, 0, stream>>>(wq, wktS, sc);
    k_sm<<<20736, 256, 0, stream>>>(sc);
    k_apply<<<apg, 512, 0, stream>>>(sc, x, ao);
    k_na<1><<<nag, 128, 0, stream>>>(x, ao, nullptr, nullptr, nullptr, tU, nullptr);
    k_fin1<<<1, 64, 0, stream>>>(tU, scl);
    k_a1<<<41472, 256, 0, stream>>>(x, ao, scl);
    // --- cross-attention: shared softmax for mask (v=p) and t3 (v=mem*p) ---
    k_proj<<<20736, 128, 0, stream>>>(x, Wct, bkc, wq);
    k_score<<<20736, 256, 0, stream>>>(wq, wktC, sc);
    k_sm<<<20736, 256, 0, stream>>>(sc);
    k_mask<<<81, 256, 0, stream>>>(sc, ps, msk);
    k_apply<<<apg, 512, 0, stream>>>(sc, memp, ao);
    k_na<2><<<nag, 128, 0, stream>>>(x, ao, msk, nullptr, nullptr, tU, tV);
    k_fin2<<<1, 64, 0, stream>>>(tU, tV, scu, scv);
    k_na<3><<<nag, 128, 0, stream>>>(x, ao, msk, scu, scv, tU, nullptr);
    k_fin1<<<1, 64, 0, stream>>>(tU, scw);
    k_a2<<<41472, 256, 0, stream>>>(x, ao, msk, scu, scv, scw);
  }

  k_o0<<<41472, 256, 0, stream>>>(x, out);
  k_o1<<<41472, 256, 0, stream>>>(x, out + (size_t)LL * BB * DD);
}

// Round 8
// 6870.005 us; speedup vs baseline: 2.3751x; 2.3751x over previous
//
#include <hip/hip_runtime.h>
#include <math.h>

#define NI  2
#define BB  32
#define DD  512
#define HWX 324
#define LL  648
#define MM  648
#define KX  128

#define TEMPF  30.0f
#define NEPSF  1e-5f
#define L2EPSF 1e-12f
#define DHWF   165888.0f
#define NSDF   0.011048543456039806f

// ---------- input staging (exact fp32 copies) --------------------------------
__global__ void k_flat(const float* __restrict__ src, float* __restrict__ x) {
  size_t idx = (size_t)blockIdx.x * 256 + threadIdx.x;
  int r = (int)(idx >> 9), d = (int)(idx & 511);
  int l = r >> 5, b = r & 31;
  int i = l / HWX, s = l % HWX;
  x[idx] = src[((size_t)(i * BB + b) * DD + d) * HWX + s];
}

__global__ void k_addpe(const float* __restrict__ pe, float* __restrict__ x) {
  size_t idx = (size_t)blockIdx.x * 256 + threadIdx.x;
  int r = (int)(idx >> 9), d = (int)(idx & 511);
  int l = r >> 5, b = r & 31;
  int i = l / HWX, s = l % HWX;
  float t = __fmul_rn(pe[((size_t)(i * BB + b) * DD + d) * HWX + s], 0.001f);
  x[idx] = __fadd_rn(x[idx], t);
}

__global__ void k_pos(const float* __restrict__ pos, float* __restrict__ ps) {
  int idx = blockIdx.x * 256 + threadIdx.x;  // 20736
  int l = idx >> 5, b = idx & 31;
  int j = l / HWX, s = l % HWX;
  ps[idx] = pos[((size_t)(j * BB + b)) * HWX + s];
}

__global__ void k_memp(const float* __restrict__ mem, const float* __restrict__ ps,
                       float* __restrict__ memp) {
  size_t idx = (size_t)blockIdx.x * 256 + threadIdx.x;
  memp[idx] = __fmul_rn(mem[idx], ps[idx >> 9]);
}

__global__ void k_wt(const float* __restrict__ W, float* __restrict__ Wt) {
  int idx = blockIdx.x * 256 + threadIdx.x;  // 65536: dst [d][k]
  int k = idx & 127, d = idx >> 7;
  Wt[idx] = W[(size_t)k * DD + d];
}

// ---------- tiled projection + bias + l2norm (bit-identical to r7 k_proj) ----
// A [20736][512]; Wt [512][128]; out[r][k] = (chain_d fmaf + bias)/max(||.||,eps)
__global__ __launch_bounds__(256) void k_projt(const float* __restrict__ A,
                                               const float* __restrict__ Wt,
                                               const float* __restrict__ bias,
                                               float* __restrict__ outp) {
  int r0 = blockIdx.x * 128;
  int tid = threadIdx.x, tx = tid & 15, ty = tid >> 4;
  __shared__ float As[128][36];
  __shared__ float Ws[32][132];
  __shared__ float bsh[128];
  __shared__ float sqb[16][129];
  __shared__ float prb[16][8];
  __shared__ float nshs[16];
  if (tid < 128) bsh[tid] = bias[tid];
  float acc[8][8] = {};
  for (int d0 = 0; d0 < 512; d0 += 32) {
#pragma unroll
    for (int n = 0; n < 4; n++) {
      int fi = tid + 256 * n;
      int rr = fi >> 3, dq = (fi & 7) * 4;
      *(float4*)&As[rr][dq] = *(const float4*)(A + (size_t)(r0 + rr) * 512 + d0 + dq);
    }
#pragma unroll
    for (int n = 0; n < 4; n++) {
      int fi = tid + 256 * n;
      int dd = fi >> 5, kq = (fi & 31) * 4;
      *(float4*)&Ws[dd][kq] = *(const float4*)(Wt + (size_t)(d0 + dd) * 128 + kq);
    }
    __syncthreads();
#pragma unroll 8
    for (int dd = 0; dd < 32; dd++) {
      float a[8], w[8];
#pragma unroll
      for (int i = 0; i < 8; i++) a[i] = As[ty + 16 * i][dd];
#pragma unroll
      for (int j = 0; j < 8; j++) w[j] = Ws[dd][tx + 16 * j];
#pragma unroll
      for (int i = 0; i < 8; i++)
#pragma unroll
        for (int j = 0; j < 8; j++) acc[i][j] = fmaf(a[i], w[j], acc[i][j]);
    }
    __syncthreads();
  }
  // epilogue: numpy pw128 per row, blocks of 16 rows (indexed by ty) per i
  for (int i = 0; i < 8; i++) {
    float val[8];
#pragma unroll
    for (int j = 0; j < 8; j++) {
      val[j] = __fadd_rn(acc[i][j], bsh[tx + 16 * j]);
      sqb[ty][tx + 16 * j] = __fmul_rn(val[j], val[j]);
    }
    __syncthreads();
    if (tid < 128) {
      int row = tid >> 3, jj = tid & 7;
      float rr = sqb[row][jj];
      for (int blk = 1; blk < 16; blk++) rr += sqb[row][blk * 8 + jj];
      prb[row][jj] = rr;
    }
    __syncthreads();
    if (tid < 16) {
      float* p = prb[tid];
      float ss = ((p[0] + p[1]) + (p[2] + p[3])) + ((p[4] + p[5]) + (p[6] + p[7]));
      nshs[tid] = fmaxf(__fsqrt_rn(ss), L2EPSF);
    }
    __syncthreads();
    float nsh = nshs[ty];
    int r = r0 + ty + 16 * i;
#pragma unroll
    for (int j = 0; j < 8; j++)
      outp[(size_t)r * 128 + tx + 16 * j] = __fdiv_rn(val[j], nsh);
    __syncthreads();
  }
}

// ---------- tiled scores: sc[(b*648+q)*648+s] = 30 * k-chain fmaf ------------
__global__ __launch_bounds__(256) void k_scoret(const float* __restrict__ wqp,
                                                const float* __restrict__ wkp,
                                                float* __restrict__ sc) {
  int q0 = blockIdx.x * 64, s0 = blockIdx.y * 64, b = blockIdx.z;
  int tid = threadIdx.x, tx = tid & 15, ty = tid >> 4;
  __shared__ float QsT[64][65];
  __shared__ float KsT[64][65];
  float acc[4][4] = {};
  const float4 f40 = make_float4(0.f, 0.f, 0.f, 0.f);
  for (int k0 = 0; k0 < 128; k0 += 64) {
#pragma unroll
    for (int n = 0; n < 4; n++) {
      int fi = tid + 256 * n;
      int rr = fi >> 4, kq = (fi & 15) * 4;
      int q = q0 + rr;
      float4 v = (q < LL) ? *(const float4*)(wqp + ((size_t)q * 32 + b) * 128 + k0 + kq) : f40;
      QsT[kq + 0][rr] = v.x; QsT[kq + 1][rr] = v.y;
      QsT[kq + 2][rr] = v.z; QsT[kq + 3][rr] = v.w;
      int s = s0 + rr;
      float4 w = (s < MM) ? *(const float4*)(wkp + ((size_t)s * 32 + b) * 128 + k0 + kq) : f40;
      KsT[kq + 0][rr] = w.x; KsT[kq + 1][rr] = w.y;
      KsT[kq + 2][rr] = w.z; KsT[kq + 3][rr] = w.w;
    }
    __syncthreads();
#pragma unroll 8
    for (int kk = 0; kk < 64; kk++) {
      float a[4], w[4];
#pragma unroll
      for (int i = 0; i < 4; i++) a[i] = QsT[kk][ty + 16 * i];
#pragma unroll
      for (int j = 0; j < 4; j++) w[j] = KsT[kk][tx + 16 * j];
#pragma unroll
      for (int i = 0; i < 4; i++)
#pragma unroll
        for (int j = 0; j < 4; j++) acc[i][j] = fmaf(a[i], w[j], acc[i][j]);
    }
    __syncthreads();
  }
#pragma unroll
  for (int i = 0; i < 4; i++) {
    int q = q0 + ty + 16 * i;
    if (q >= LL) continue;
    float* orow = sc + ((size_t)b * LL + q) * MM;
#pragma unroll
    for (int j = 0; j < 4; j++) {
      int s = s0 + tx + 16 * j;
      if (s < MM) orow[s] = __fmul_rn(acc[i][j], TEMPF);
    }
  }
}

// ---------- softmax: identical math, pw648 via 64 independent lanes ----------
__global__ __launch_bounds__(256) void k_sm2(float* __restrict__ sc) {
  int row = blockIdx.x;
  float* p = sc + (size_t)row * MM;
  int t = threadIdx.x;
  __shared__ float red[256];
  __shared__ float es[MM];
  __shared__ float prc[64];
  __shared__ float ssum;
  float v0 = p[t], v1 = p[t + 256];
  bool h2 = t < (MM - 512);
  float v2 = h2 ? p[t + 512] : -3.0e38f;
  red[t] = fmaxf(fmaxf(v0, v1), v2);
  __syncthreads();
  for (int off = 128; off; off >>= 1) {
    if (t < off) red[t] = fmaxf(red[t], red[t + off]);
    __syncthreads();
  }
  float mx = red[0];
  float e0 = (float)exp((double)__fsub_rn(v0, mx));
  float e1 = (float)exp((double)__fsub_rn(v1, mx));
  float e2 = h2 ? (float)exp((double)__fsub_rn(v2, mx)) : 0.0f;
  es[t] = e0; es[t + 256] = e1;
  if (h2) es[t + 512] = e2;
  __syncthreads();
  if (t < 64) {  // chunk c: base 80c, len 80 (88 for c=7); lane jj = accumulator
    int c = t >> 3, jj = t & 7;
    int base = c * 80, n = (c == 7) ? 88 : 80;
    float r = es[base + jj];
    for (int i = 8; i < n; i += 8) r += es[base + i + jj];
    prc[t] = r;
  }
  __syncthreads();
  if (t == 0) {
    float pc[8];
#pragma unroll
    for (int c = 0; c < 8; c++) {
      float* pp = prc + c * 8;
      pc[c] = ((pp[0] + pp[1]) + (pp[2] + pp[3])) + ((pp[4] + pp[5]) + (pp[6] + pp[7]));
    }
    float lsum = (pc[0] + pc[1]) + (pc[2] + pc[3]);
    float rsum = (pc[4] + pc[5]) + (pc[6] + pc[7]);
    ssum = lsum + rsum;
  }
  __syncthreads();
  float s = ssum;
  p[t] = __fdiv_rn(e0, s);
  p[t + 256] = __fdiv_rn(e1, s);
  if (h2) p[t + 512] = __fdiv_rn(e2, s);
}

// ---------- tiled apply: out[(q*32+b)][d] = s-chain fmaf (s ascending) -------
__global__ __launch_bounds__(256) void k_applyt(const float* __restrict__ aff,
                                                const float* __restrict__ V,
                                                float* __restrict__ outp) {
  int q0 = blockIdx.x * 128, d0 = blockIdx.y * 128, b = blockIdx.z;
  int tid = threadIdx.x, tx = tid & 15, ty = tid >> 4;
  __shared__ float As[128][36];
  __shared__ float Vs[32][132];
  float acc[8][8] = {};
  const float4 f40 = make_float4(0.f, 0.f, 0.f, 0.f);
  for (int s0 = 0; s0 < 672; s0 += 32) {
#pragma unroll
    for (int n = 0; n < 4; n++) {
      int fi = tid + 256 * n;
      int rr = fi >> 3, sq = (fi & 7) * 4;
      int q = q0 + rr;
      float4 v = (q < LL && (s0 + sq) < MM)
                     ? *(const float4*)(aff + ((size_t)b * LL + q) * MM + s0 + sq)
                     : f40;
      *(float4*)&As[rr][sq] = v;
    }
#pragma unroll
    for (int n = 0; n < 4; n++) {
      int fi = tid + 256 * n;
      int sr = fi >> 5, dq = (fi & 31) * 4;
      int s = s0 + sr;
      float4 v = (s < MM) ? *(const float4*)(V + ((size_t)s * 32 + b) * 512 + d0 + dq) : f40;
      *(float4*)&Vs[sr][dq] = v;
    }
    __syncthreads();
#pragma unroll 8
    for (int ss = 0; ss < 32; ss++) {
      float a[8], w[8];
#pragma unroll
      for (int i = 0; i < 8; i++) a[i] = As[ty + 16 * i][ss];
#pragma unroll
      for (int j = 0; j < 8; j++) w[j] = Vs[ss][tx + 16 * j];
#pragma unroll
      for (int i = 0; i < 8; i++)
#pragma unroll
        for (int j = 0; j < 8; j++) acc[i][j] = fmaf(a[i], w[j], acc[i][j]);
    }
    __syncthreads();
  }
#pragma unroll
  for (int i = 0; i < 8; i++) {
    int q = q0 + ty + 16 * i;
    if (q >= LL) continue;
    float* orow = outp + ((size_t)q * 32 + b) * 512 + d0;
#pragma unroll
    for (int j = 0; j < 8; j++) orow[tx + 16 * j] = acc[i][j];
  }
}

// ---------- mask[q*32+b] = s-chain fmaf --------------------------------------
__global__ void k_mask(const float* __restrict__ sc, const float* __restrict__ ps,
                       float* __restrict__ msk) {
  int tid = blockIdx.x * 256 + threadIdx.x;
  if (tid >= BB * LL) return;
  int b = tid / LL, q = tid % LL;
  const float* arow = sc + (size_t)tid * MM;
  float acc = 0.0f;
  for (int s = 0; s < MM; s++) acc = fmaf(arow[s], ps[s * BB + b], acc);
  msk[q * BB + b] = acc;
}

// ---------- instance-norm stage A (verbatim round 7) -------------------------
template <int MODE>
__global__ __launch_bounds__(128) void k_na(const float* __restrict__ x,
                                            const float* __restrict__ ao,
                                            const float* __restrict__ msk,
                                            const float* __restrict__ scu,
                                            const float* __restrict__ scv,
                                            float* __restrict__ tU,
                                            float* __restrict__ tV) {
  int s = blockIdx.x;
  int g = blockIdx.y;
  int i = g >> 5, b = g & 31;
  int l = i * HWX + s;
  size_t base = ((size_t)l * BB + b) * DD;
  int t = threadIdx.x;
  __shared__ float squ[DD];
  __shared__ float sqv[DD];
  __shared__ float pru[32];
  __shared__ float prv[32];
  float mk = 0.f, su = 0.f, sv = 0.f;
  if (MODE >= 2) mk = msk[l * BB + b];
  if (MODE == 3) { su = scu[g]; sv = scv[g]; }
  for (int d = t; d < DD; d += 128) {
    float xx = x[base + d];
    if (MODE == 1) {
      float y = __fadd_rn(xx, ao[base + d]);
      squ[d] = __fmul_rn(y, y);
    } else if (MODE == 2) {
      float u = __fmul_rn(xx, mk);
      float v = __fadd_rn(xx, ao[base + d]);
      squ[d] = __fmul_rn(u, u);
      sqv[d] = __fmul_rn(v, v);
    } else {
      float u = __fmul_rn(xx, mk);
      float v = __fadd_rn(xx, ao[base + d]);
      float t2 = __fmul_rn(u, su);
      float t4 = __fmul_rn(v, sv);
      float w = __fadd_rn(t2, t4);
      squ[d] = __fmul_rn(w, w);
    }
  }
  __syncthreads();
  if (t < 32) {
    int c = t >> 3, jj = t & 7, b0 = c * 128;
    float r = squ[b0 + jj];
    for (int blk = 1; blk < 16; blk++) r += squ[b0 + blk * 8 + jj];
    pru[t] = r;
    if (MODE == 2) {
      float r2 = sqv[b0 + jj];
      for (int blk = 1; blk < 16; blk++) r2 += sqv[b0 + blk * 8 + jj];
      prv[t] = r2;
    }
  }
  __syncthreads();
  if (t == 0) {
    float cc[4];
    for (int c = 0; c < 4; c++)
      cc[c] = ((pru[c * 8] + pru[c * 8 + 1]) + (pru[c * 8 + 2] + pru[c * 8 + 3])) +
              ((pru[c * 8 + 4] + pru[c * 8 + 5]) + (pru[c * 8 + 6] + pru[c * 8 + 7]));
    tU[g * HWX + s] = (cc[0] + cc[1]) + (cc[2] + cc[3]);
    if (MODE == 2) {
      for (int c = 0; c < 4; c++)
        cc[c] = ((prv[c * 8] + prv[c * 8 + 1]) + (prv[c * 8 + 2] + prv[c * 8 + 3])) +
                ((prv[c * 8 + 4] + prv[c * 8 + 5]) + (prv[c * 8 + 6] + prv[c * 8 + 7]));
      tV[g * HWX + s] = (cc[0] + cc[1]) + (cc[2] + cc[3]);
    }
  }
}

__global__ void k_fin1(const float* __restrict__ tU, float* __restrict__ scl) {
  int g = threadIdx.x;
  float ss = 0.0f;
  for (int s = 0; s < HWX; s++) ss += tU[g * HWX + s];
  scl[g] = __fmul_rn(NSDF, __fsqrt_rn(__fdiv_rn(DHWF, __fadd_rn(ss, NEPSF))));
}

__global__ void k_fin2(const float* __restrict__ tU, const float* __restrict__ tV,
                       float* __restrict__ scu, float* __restrict__ scv) {
  int g = threadIdx.x;
  float su = 0.0f, sv = 0.0f;
  for (int s = 0; s < HWX; s++) { su += tU[g * HWX + s]; sv += tV[g * HWX + s]; }
  scu[g] = __fmul_rn(NSDF, __fsqrt_rn(__fdiv_rn(DHWF, __fadd_rn(su, NEPSF))));
  scv[g] = __fmul_rn(NSDF, __fsqrt_rn(__fdiv_rn(DHWF, __fadd_rn(sv, NEPSF))));
}

__global__ void k_a1(float* __restrict__ x, const float* __restrict__ ao,
                     const float* __restrict__ scl) {
  size_t idx = (size_t)blockIdx.x * 256 + threadIdx.x;
  int r = (int)(idx >> 9);
  int l = r >> 5, b = r & 31;
  int g = (l / HWX) * BB + b;
  x[idx] = __fmul_rn(__fadd_rn(x[idx], ao[idx]), scl[g]);
}

__global__ void k_a2(float* __restrict__ x, const float* __restrict__ ao,
                     const float* __restrict__ msk, const float* __restrict__ scu,
                     const float* __restrict__ scv, const float* __restrict__ scw) {
  size_t idx = (size_t)blockIdx.x * 256 + threadIdx.x;
  int r = (int)(idx >> 9);
  int l = r >> 5, b = r & 31;
  int g = (l / HWX) * BB + b;
  float mk = msk[l * BB + b];
  float xx = x[idx];
  float u = __fmul_rn(xx, mk);
  float v = __fadd_rn(xx, ao[idx]);
  float t2 = __fmul_rn(u, scu[g]);
  float t4 = __fmul_rn(v, scv[g]);
  float w = __fadd_rn(t2, t4);
  x[idx] = __fmul_rn(w, scw[g]);
}

// ---------- outputs ----------------------------------------------------------
__global__ void k_o0(const float* __restrict__ x, float* __restrict__ out) {
  size_t idx = (size_t)blockIdx.x * 256 + threadIdx.x;
  out[idx] = x[idx];
}

__global__ void k_o1(const float* __restrict__ x, float* __restrict__ out1) {
  size_t idx = (size_t)blockIdx.x * 256 + threadIdx.x;
  int s = (int)(idx % HWX);
  int d = (int)((idx / HWX) & 511);
  int ib = (int)(idx / ((size_t)HWX * DD));
  int i = ib >> 5, b = ib & 31;
  int l = i * HWX + s;
  out1[idx] = x[((size_t)l * BB + b) * DD + d];
}

// ---------------------------------------------------------------------------
extern "C" void kernel_launch(void* const* d_in, const int* in_sizes, int n_in,
                              void* d_out, int out_size, void* d_ws, size_t ws_size,
                              hipStream_t stream) {
  const float* tgt = (const float*)d_in[0];
  const float* pe  = (const float*)d_in[1];
  const float* mem = (const float*)d_in[2];
  const float* pos = (const float*)d_in[3];
  const float* Wks = (const float*)d_in[4];
  const float* bks = (const float*)d_in[5];
  const float* Wkc = (const float*)d_in[6];
  const float* bkc = (const float*)d_in[7];
  float* out = (float*)d_out;

  // 50,810,112 floats = 203,240,448 bytes
  if (ws_size < (size_t)203240448) return;
  float* f = (float*)d_ws;
  float* x    = f;                  // 10,616,832  [l,b,d]
  float* ao   = f + 10616832;       // 10,616,832
  float* memp = f + 21233664;       // 10,616,832
  float* wq   = f + 31850496;       //  2,654,208  [l,b,k]
  float* wkm  = f + 34504704;       //  2,654,208
  float* sc   = f + 37158912;       // 13,436,928  [b,q,s]
  float* msk  = f + 50595840;       //     20,736  [q,b]
  float* ps   = f + 50616576;       //     20,736  [l,b]
  float* tU   = f + 50637312;       //     20,736
  float* tV   = f + 50658048;       //     20,736
  float* scl  = f + 50678784;       //        256
  float* scu  = scl + 64;
  float* scv  = scl + 128;
  float* scw  = scl + 192;
  float* Wst  = f + 50679040;       //     65,536  [d,k]
  float* Wct  = f + 50744576;       //     65,536

  k_wt<<<256, 256, 0, stream>>>(Wks, Wst);
  k_wt<<<256, 256, 0, stream>>>(Wkc, Wct);
  k_flat<<<41472, 256, 0, stream>>>(tgt, x);
  k_pos<<<81, 256, 0, stream>>>(pos, ps);
  k_memp<<<41472, 256, 0, stream>>>(mem, ps, memp);
  // loop-invariant cross keys from memory
  k_projt<<<162, 256, 0, stream>>>(mem, Wct, bkc, wkm);

  dim3 scg(11, 11, 32);
  dim3 apg(6, 4, 32);
  dim3 nag(324, 64);
  for (int l = 0; l < 6; l++) {
    k_addpe<<<41472, 256, 0, stream>>>(pe, x);
    // --- self-attention (q=k=v=x) ---
    k_projt<<<162, 256, 0, stream>>>(x, Wst, bks, wq);
    k_scoret<<<scg, 256, 0, stream>>>(wq, wq, sc);
    k_sm2<<<20736, 256, 0, stream>>>(sc);
    k_applyt<<<apg, 256, 0, stream>>>(sc, x, ao);
    k_na<1><<<nag, 128, 0, stream>>>(x, ao, nullptr, nullptr, nullptr, tU, nullptr);
    k_fin1<<<1, 64, 0, stream>>>(tU, scl);
    k_a1<<<41472, 256, 0, stream>>>(x, ao, scl);
    // --- cross-attention: shared softmax for mask (v=p) and t3 (v=mem*p) ---
    k_projt<<<162, 256, 0, stream>>>(x, Wct, bkc, wq);
    k_scoret<<<scg, 256, 0, stream>>>(wq, wkm, sc);
    k_sm2<<<20736, 256, 0, stream>>>(sc);
    k_mask<<<81, 256, 0, stream>>>(sc, ps, msk);
    k_applyt<<<apg, 256, 0, stream>>>(sc, memp, ao);
    k_na<2><<<nag, 128, 0, stream>>>(x, ao, msk, nullptr, nullptr, tU, tV);
    k_fin2<<<1, 64, 0, stream>>>(tU, tV, scu, scv);
    k_na<3><<<nag, 128, 0, stream>>>(x, ao, msk, scu, scv, tU, nullptr);
    k_fin1<<<1, 64, 0, stream>>>(tU, scw);
    k_a2<<<41472, 256, 0, stream>>>(x, ao, msk, scu, scv, scw);
  }

  k_o0<<<41472, 256, 0, stream>>>(x, out);
  k_o1<<<41472, 256, 0, stream>>>(x, out + (size_t)LL * BB * DD);
}

// Round 9
// 6584.255 us; speedup vs baseline: 2.4781x; 1.0434x over previous
//
#include <hip/hip_runtime.h>
#include <math.h>

#define NI  2
#define BB  32
#define DD  512
#define HWX 324
#define LL  648
#define MM  648
#define KX  128

#define TEMPF  30.0f
#define NEPSF  1e-5f
#define L2EPSF 1e-12f
#define DHWF   165888.0f
#define NSDF   0.011048543456039806f

// ---------- input staging (exact fp32 copies) --------------------------------
__global__ void k_flat(const float* __restrict__ src, float* __restrict__ x) {
  size_t idx = (size_t)blockIdx.x * 256 + threadIdx.x;
  int r = (int)(idx >> 9), d = (int)(idx & 511);
  int l = r >> 5, b = r & 31;
  int i = l / HWX, s = l % HWX;
  x[idx] = src[((size_t)(i * BB + b) * DD + d) * HWX + s];
}

__global__ void k_addpe(const float* __restrict__ pe, float* __restrict__ x) {
  size_t idx = (size_t)blockIdx.x * 256 + threadIdx.x;
  int r = (int)(idx >> 9), d = (int)(idx & 511);
  int l = r >> 5, b = r & 31;
  int i = l / HWX, s = l % HWX;
  float t = __fmul_rn(pe[((size_t)(i * BB + b) * DD + d) * HWX + s], 0.001f);
  x[idx] = __fadd_rn(x[idx], t);
}

__global__ void k_pos(const float* __restrict__ pos, float* __restrict__ ps) {
  int idx = blockIdx.x * 256 + threadIdx.x;  // 20736
  int l = idx >> 5, b = idx & 31;
  int j = l / HWX, s = l % HWX;
  ps[idx] = pos[((size_t)(j * BB + b)) * HWX + s];
}

__global__ void k_memp(const float* __restrict__ mem, const float* __restrict__ ps,
                       float* __restrict__ memp) {
  size_t idx = (size_t)blockIdx.x * 256 + threadIdx.x;
  memp[idx] = __fmul_rn(mem[idx], ps[idx >> 9]);
}

__global__ void k_wt(const float* __restrict__ W, float* __restrict__ Wt) {
  int idx = blockIdx.x * 256 + threadIdx.x;  // 65536: dst [d][k]
  int k = idx & 127, d = idx >> 7;
  Wt[idx] = W[(size_t)k * DD + d];
}

// ---------- tiled projection + bias + l2norm (chains identical to r7) --------
__global__ __launch_bounds__(256) void k_projt(const float* __restrict__ A,
                                               const float* __restrict__ Wt,
                                               const float* __restrict__ bias,
                                               float* __restrict__ outp) {
  int r0 = blockIdx.x * 128;
  int tid = threadIdx.x, tx = tid & 15, ty = tid >> 4;
  __shared__ float As[128][36];
  __shared__ float Ws[32][132];
  __shared__ float bsh[128];
  __shared__ float sqb[16][129];
  __shared__ float prb[16][8];
  __shared__ float nshs[16];
  if (tid < 128) bsh[tid] = bias[tid];
  float acc[8][8] = {};
  for (int d0 = 0; d0 < 512; d0 += 32) {
#pragma unroll
    for (int n = 0; n < 4; n++) {
      int fi = tid + 256 * n;
      int rr = fi >> 3, dq = (fi & 7) * 4;
      *(float4*)&As[rr][dq] = *(const float4*)(A + (size_t)(r0 + rr) * 512 + d0 + dq);
    }
#pragma unroll
    for (int n = 0; n < 4; n++) {
      int fi = tid + 256 * n;
      int dd = fi >> 5, kq = (fi & 31) * 4;
      *(float4*)&Ws[dd][kq] = *(const float4*)(Wt + (size_t)(d0 + dd) * 128 + kq);
    }
    __syncthreads();
#pragma unroll 8
    for (int dd = 0; dd < 32; dd++) {
      float a[8], w[8];
#pragma unroll
      for (int i = 0; i < 8; i++) a[i] = As[ty + 16 * i][dd];
#pragma unroll
      for (int j = 0; j < 8; j++) w[j] = Ws[dd][tx + 16 * j];
#pragma unroll
      for (int i = 0; i < 8; i++)
#pragma unroll
        for (int j = 0; j < 8; j++) acc[i][j] = fmaf(a[i], w[j], acc[i][j]);
    }
    __syncthreads();
  }
  for (int i = 0; i < 8; i++) {
    float val[8];
#pragma unroll
    for (int j = 0; j < 8; j++) {
      val[j] = __fadd_rn(acc[i][j], bsh[tx + 16 * j]);
      sqb[ty][tx + 16 * j] = __fmul_rn(val[j], val[j]);
    }
    __syncthreads();
    if (tid < 128) {
      int row = tid >> 3, jj = tid & 7;
      float rr = sqb[row][jj];
      for (int blk = 1; blk < 16; blk++) rr += sqb[row][blk * 8 + jj];
      prb[row][jj] = rr;
    }
    __syncthreads();
    if (tid < 16) {
      float* p = prb[tid];
      float ss = ((p[0] + p[1]) + (p[2] + p[3])) + ((p[4] + p[5]) + (p[6] + p[7]));
      nshs[tid] = fmaxf(__fsqrt_rn(ss), L2EPSF);
    }
    __syncthreads();
    float nsh = nshs[ty];
    int r = r0 + ty + 16 * i;
#pragma unroll
    for (int j = 0; j < 8; j++)
      outp[(size_t)r * 128 + tx + 16 * j] = __fdiv_rn(val[j], nsh);
    __syncthreads();
  }
}

// ---------- tiled scores: sc[(b*648+q)*648+s] = 30 * k-chain fmaf ------------
__global__ __launch_bounds__(256) void k_scoret(const float* __restrict__ wqp,
                                                const float* __restrict__ wkp,
                                                float* __restrict__ sc) {
  int q0 = blockIdx.x * 64, s0 = blockIdx.y * 64, b = blockIdx.z;
  int tid = threadIdx.x, tx = tid & 15, ty = tid >> 4;
  __shared__ float QsT[64][65];
  __shared__ float KsT[64][65];
  float acc[4][4] = {};
  const float4 f40 = make_float4(0.f, 0.f, 0.f, 0.f);
  for (int k0 = 0; k0 < 128; k0 += 64) {
#pragma unroll
    for (int n = 0; n < 4; n++) {
      int fi = tid + 256 * n;
      int rr = fi >> 4, kq = (fi & 15) * 4;
      int q = q0 + rr;
      float4 v = (q < LL) ? *(const float4*)(wqp + ((size_t)q * 32 + b) * 128 + k0 + kq) : f40;
      QsT[kq + 0][rr] = v.x; QsT[kq + 1][rr] = v.y;
      QsT[kq + 2][rr] = v.z; QsT[kq + 3][rr] = v.w;
      int s = s0 + rr;
      float4 w = (s < MM) ? *(const float4*)(wkp + ((size_t)s * 32 + b) * 128 + k0 + kq) : f40;
      KsT[kq + 0][rr] = w.x; KsT[kq + 1][rr] = w.y;
      KsT[kq + 2][rr] = w.z; KsT[kq + 3][rr] = w.w;
    }
    __syncthreads();
#pragma unroll 8
    for (int kk = 0; kk < 64; kk++) {
      float a[4], w[4];
#pragma unroll
      for (int i = 0; i < 4; i++) a[i] = QsT[kk][ty + 16 * i];
#pragma unroll
      for (int j = 0; j < 4; j++) w[j] = KsT[kk][tx + 16 * j];
#pragma unroll
      for (int i = 0; i < 4; i++)
#pragma unroll
        for (int j = 0; j < 4; j++) acc[i][j] = fmaf(a[i], w[j], acc[i][j]);
    }
    __syncthreads();
  }
#pragma unroll
  for (int i = 0; i < 4; i++) {
    int q = q0 + ty + 16 * i;
    if (q >= LL) continue;
    float* orow = sc + ((size_t)b * LL + q) * MM;
#pragma unroll
    for (int j = 0; j < 4; j++) {
      int s = s0 + tx + 16 * j;
      if (s < MM) orow[s] = __fmul_rn(acc[i][j], TEMPF);
    }
  }
}

// ---------- softmax: identical math, pw648 via 64 independent lanes ----------
__global__ __launch_bounds__(256) void k_sm2(float* __restrict__ sc) {
  int row = blockIdx.x;
  float* p = sc + (size_t)row * MM;
  int t = threadIdx.x;
  __shared__ float red[256];
  __shared__ float es[MM];
  __shared__ float prc[64];
  __shared__ float ssum;
  float v0 = p[t], v1 = p[t + 256];
  bool h2 = t < (MM - 512);
  float v2 = h2 ? p[t + 512] : -3.0e38f;
  red[t] = fmaxf(fmaxf(v0, v1), v2);
  __syncthreads();
  for (int off = 128; off; off >>= 1) {
    if (t < off) red[t] = fmaxf(red[t], red[t + off]);
    __syncthreads();
  }
  float mx = red[0];
  float e0 = (float)exp((double)__fsub_rn(v0, mx));
  float e1 = (float)exp((double)__fsub_rn(v1, mx));
  float e2 = h2 ? (float)exp((double)__fsub_rn(v2, mx)) : 0.0f;
  es[t] = e0; es[t + 256] = e1;
  if (h2) es[t + 512] = e2;
  __syncthreads();
  if (t < 64) {
    int c = t >> 3, jj = t & 7;
    int base = c * 80, n = (c == 7) ? 88 : 80;
    float r = es[base + jj];
    for (int i = 8; i < n; i += 8) r += es[base + i + jj];
    prc[t] = r;
  }
  __syncthreads();
  if (t == 0) {
    float pc[8];
#pragma unroll
    for (int c = 0; c < 8; c++) {
      float* pp = prc + c * 8;
      pc[c] = ((pp[0] + pp[1]) + (pp[2] + pp[3])) + ((pp[4] + pp[5]) + (pp[6] + pp[7]));
    }
    float lsum = (pc[0] + pc[1]) + (pc[2] + pc[3]);
    float rsum = (pc[4] + pc[5]) + (pc[6] + pc[7]);
    ssum = lsum + rsum;
  }
  __syncthreads();
  float s = ssum;
  p[t] = __fdiv_rn(e0, s);
  p[t + 256] = __fdiv_rn(e1, s);
  if (h2) p[t + 512] = __fdiv_rn(e2, s);
}

// ---------- fused apply: 16-q slab in LDS, full D per block, optional mask ---
// out[(q*32+b)][d] = s-chain fmaf (s ascending); mask[q*32+b] = s-chain vs ps
template <int DO_MASK>
__global__ __launch_bounds__(256) void k_applyf(const float* __restrict__ aff,
                                                const float* __restrict__ V,
                                                const float* __restrict__ ps,
                                                float* __restrict__ outp,
                                                float* __restrict__ msk) {
  int q0 = blockIdx.x * 16;
  int b = blockIdx.y;
  int tid = threadIdx.x;
  __shared__ float affs[16][648];
  const float4 f40 = make_float4(0.f, 0.f, 0.f, 0.f);
#pragma unroll
  for (int n = 0; n < 11; n++) {  // 16*162 = 2592 float4
    int fi = tid + 256 * n;
    if (fi < 2592) {
      int rr = fi / 162, c4 = fi - rr * 162;
      int q = q0 + rr;
      float4 v = (q < LL) ? *(const float4*)(aff + ((size_t)b * LL + q) * MM + c4 * 4)
                          : f40;
      *(float4*)&affs[rr][c4 * 4] = v;
    }
  }
  __syncthreads();
  float acc0[16] = {};
  float acc1[16] = {};
  for (int sg = 0; sg < 162; sg++) {
    float4 av[16];
#pragma unroll
    for (int qq = 0; qq < 16; qq++) av[qq] = *(float4*)&affs[qq][sg * 4];
#pragma unroll
    for (int e = 0; e < 4; e++) {
      int s = sg * 4 + e;
      float2 vv = *(const float2*)(V + ((size_t)s * 32 + b) * 512 + tid * 2);
#pragma unroll
      for (int qq = 0; qq < 16; qq++) {
        float a = (e == 0) ? av[qq].x : (e == 1) ? av[qq].y : (e == 2) ? av[qq].z : av[qq].w;
        acc0[qq] = fmaf(a, vv.x, acc0[qq]);
        acc1[qq] = fmaf(a, vv.y, acc1[qq]);
      }
    }
  }
#pragma unroll
  for (int qq = 0; qq < 16; qq++) {
    int q = q0 + qq;
    if (q < LL) {
      float2 r = make_float2(acc0[qq], acc1[qq]);
      *(float2*)(outp + ((size_t)q * 32 + b) * 512 + tid * 2) = r;
    }
  }
  if (DO_MASK && tid < 16) {
    int q = q0 + tid;
    if (q < LL) {
      float a = 0.0f;
      for (int s = 0; s < MM; s++) a = fmaf(affs[tid][s], ps[s * 32 + b], a);
      msk[q * 32 + b] = a;
    }
  }
}

// ---------- instance-norm stage A (verbatim) ---------------------------------
template <int MODE>
__global__ __launch_bounds__(128) void k_na(const float* __restrict__ x,
                                            const float* __restrict__ ao,
                                            const float* __restrict__ msk,
                                            const float* __restrict__ scu,
                                            const float* __restrict__ scv,
                                            float* __restrict__ tU,
                                            float* __restrict__ tV) {
  int s = blockIdx.x;
  int g = blockIdx.y;
  int i = g >> 5, b = g & 31;
  int l = i * HWX + s;
  size_t base = ((size_t)l * BB + b) * DD;
  int t = threadIdx.x;
  __shared__ float squ[DD];
  __shared__ float sqv[DD];
  __shared__ float pru[32];
  __shared__ float prv[32];
  float mk = 0.f, su = 0.f, sv = 0.f;
  if (MODE >= 2) mk = msk[l * BB + b];
  if (MODE == 3) { su = scu[g]; sv = scv[g]; }
  for (int d = t; d < DD; d += 128) {
    float xx = x[base + d];
    if (MODE == 1) {
      float y = __fadd_rn(xx, ao[base + d]);
      squ[d] = __fmul_rn(y, y);
    } else if (MODE == 2) {
      float u = __fmul_rn(xx, mk);
      float v = __fadd_rn(xx, ao[base + d]);
      squ[d] = __fmul_rn(u, u);
      sqv[d] = __fmul_rn(v, v);
    } else {
      float u = __fmul_rn(xx, mk);
      float v = __fadd_rn(xx, ao[base + d]);
      float t2 = __fmul_rn(u, su);
      float t4 = __fmul_rn(v, sv);
      float w = __fadd_rn(t2, t4);
      squ[d] = __fmul_rn(w, w);
    }
  }
  __syncthreads();
  if (t < 32) {
    int c = t >> 3, jj = t & 7, b0 = c * 128;
    float r = squ[b0 + jj];
    for (int blk = 1; blk < 16; blk++) r += squ[b0 + blk * 8 + jj];
    pru[t] = r;
    if (MODE == 2) {
      float r2 = sqv[b0 + jj];
      for (int blk = 1; blk < 16; blk++) r2 += sqv[b0 + blk * 8 + jj];
      prv[t] = r2;
    }
  }
  __syncthreads();
  if (t == 0) {
    float cc[4];
    for (int c = 0; c < 4; c++)
      cc[c] = ((pru[c * 8] + pru[c * 8 + 1]) + (pru[c * 8 + 2] + pru[c * 8 + 3])) +
              ((pru[c * 8 + 4] + pru[c * 8 + 5]) + (pru[c * 8 + 6] + pru[c * 8 + 7]));
    tU[g * HWX + s] = (cc[0] + cc[1]) + (cc[2] + cc[3]);
    if (MODE == 2) {
      for (int c = 0; c < 4; c++)
        cc[c] = ((prv[c * 8] + prv[c * 8 + 1]) + (prv[c * 8 + 2] + prv[c * 8 + 3])) +
                ((prv[c * 8 + 4] + prv[c * 8 + 5]) + (prv[c * 8 + 6] + prv[c * 8 + 7]));
      tV[g * HWX + s] = (cc[0] + cc[1]) + (cc[2] + cc[3]);
    }
  }
}

__global__ void k_fin1(const float* __restrict__ tU, float* __restrict__ scl) {
  int g = threadIdx.x;
  float ss = 0.0f;
  for (int s = 0; s < HWX; s++) ss += tU[g * HWX + s];
  scl[g] = __fmul_rn(NSDF, __fsqrt_rn(__fdiv_rn(DHWF, __fadd_rn(ss, NEPSF))));
}

__global__ void k_fin2(const float* __restrict__ tU, const float* __restrict__ tV,
                       float* __restrict__ scu, float* __restrict__ scv) {
  int g = threadIdx.x;
  float su = 0.0f, sv = 0.0f;
  for (int s = 0; s < HWX; s++) { su += tU[g * HWX + s]; sv += tV[g * HWX + s]; }
  scu[g] = __fmul_rn(NSDF, __fsqrt_rn(__fdiv_rn(DHWF, __fadd_rn(su, NEPSF))));
  scv[g] = __fmul_rn(NSDF, __fsqrt_rn(__fdiv_rn(DHWF, __fadd_rn(sv, NEPSF))));
}

__global__ void k_a1(float* __restrict__ x, const float* __restrict__ ao,
                     const float* __restrict__ scl) {
  size_t idx = (size_t)blockIdx.x * 256 + threadIdx.x;
  int r = (int)(idx >> 9);
  int l = r >> 5, b = r & 31;
  int g = (l / HWX) * BB + b;
  x[idx] = __fmul_rn(__fadd_rn(x[idx], ao[idx]), scl[g]);
}

__global__ void k_a2(float* __restrict__ x, const float* __restrict__ ao,
                     const float* __restrict__ msk, const float* __restrict__ scu,
                     const float* __restrict__ scv, const float* __restrict__ scw) {
  size_t idx = (size_t)blockIdx.x * 256 + threadIdx.x;
  int r = (int)(idx >> 9);
  int l = r >> 5, b = r & 31;
  int g = (l / HWX) * BB + b;
  float mk = msk[l * BB + b];
  float xx = x[idx];
  float u = __fmul_rn(xx, mk);
  float v = __fadd_rn(xx, ao[idx]);
  float t2 = __fmul_rn(u, scu[g]);
  float t4 = __fmul_rn(v, scv[g]);
  float w = __fadd_rn(t2, t4);
  x[idx] = __fmul_rn(w, scw[g]);
}

// ---------- outputs ----------------------------------------------------------
__global__ void k_o0(const float* __restrict__ x, float* __restrict__ out) {
  size_t idx = (size_t)blockIdx.x * 256 + threadIdx.x;
  out[idx] = x[idx];
}

__global__ void k_o1(const float* __restrict__ x, float* __restrict__ out1) {
  size_t idx = (size_t)blockIdx.x * 256 + threadIdx.x;
  int s = (int)(idx % HWX);
  int d = (int)((idx / HWX) & 511);
  int ib = (int)(idx / ((size_t)HWX * DD));
  int i = ib >> 5, b = ib & 31;
  int l = i * HWX + s;
  out1[idx] = x[((size_t)l * BB + b) * DD + d];
}

// ---------------------------------------------------------------------------
extern "C" void kernel_launch(void* const* d_in, const int* in_sizes, int n_in,
                              void* d_out, int out_size, void* d_ws, size_t ws_size,
                              hipStream_t stream) {
  const float* tgt = (const float*)d_in[0];
  const float* pe  = (const float*)d_in[1];
  const float* mem = (const float*)d_in[2];
  const float* pos = (const float*)d_in[3];
  const float* Wks = (const float*)d_in[4];
  const float* bks = (const float*)d_in[5];
  const float* Wkc = (const float*)d_in[6];
  const float* bkc = (const float*)d_in[7];
  float* out = (float*)d_out;

  // 50,810,112 floats = 203,240,448 bytes
  if (ws_size < (size_t)203240448) return;
  float* f = (float*)d_ws;
  float* x    = f;                  // 10,616,832  [l,b,d]
  float* ao   = f + 10616832;       // 10,616,832
  float* memp = f + 21233664;       // 10,616,832
  float* wq   = f + 31850496;       //  2,654,208  [l,b,k]
  float* wkm  = f + 34504704;       //  2,654,208
  float* sc   = f + 37158912;       // 13,436,928  [b,q,s]
  float* msk  = f + 50595840;       //     20,736  [q,b]
  float* ps   = f + 50616576;       //     20,736  [l,b]
  float* tU   = f + 50637312;       //     20,736
  float* tV   = f + 50658048;       //     20,736
  float* scl  = f + 50678784;       //        256
  float* scu  = scl + 64;
  float* scv  = scl + 128;
  float* scw  = scl + 192;
  float* Wst  = f + 50679040;       //     65,536  [d,k]
  float* Wct  = f + 50744576;       //     65,536

  k_wt<<<256, 256, 0, stream>>>(Wks, Wst);
  k_wt<<<256, 256, 0, stream>>>(Wkc, Wct);
  k_flat<<<41472, 256, 0, stream>>>(tgt, x);
  k_pos<<<81, 256, 0, stream>>>(pos, ps);
  k_memp<<<41472, 256, 0, stream>>>(mem, ps, memp);
  // loop-invariant cross keys from memory
  k_projt<<<162, 256, 0, stream>>>(mem, Wct, bkc, wkm);

  dim3 scg(11, 11, 32);
  dim3 apg(41, 32);
  dim3 nag(324, 64);
  for (int l = 0; l < 6; l++) {
    k_addpe<<<41472, 256, 0, stream>>>(pe, x);
    // --- self-attention (q=k=v=x) ---
    k_projt<<<162, 256, 0, stream>>>(x, Wst, bks, wq);
    k_scoret<<<scg, 256, 0, stream>>>(wq, wq, sc);
    k_sm2<<<20736, 256, 0, stream>>>(sc);
    k_applyf<0><<<apg, 256, 0, stream>>>(sc, x, nullptr, ao, nullptr);
    k_na<1><<<nag, 128, 0, stream>>>(x, ao, nullptr, nullptr, nullptr, tU, nullptr);
    k_fin1<<<1, 64, 0, stream>>>(tU, scl);
    k_a1<<<41472, 256, 0, stream>>>(x, ao, scl);
    // --- cross-attention: shared softmax; mask folded into apply ---
    k_projt<<<162, 256, 0, stream>>>(x, Wct, bkc, wq);
    k_scoret<<<scg, 256, 0, stream>>>(wq, wkm, sc);
    k_sm2<<<20736, 256, 0, stream>>>(sc);
    k_applyf<1><<<apg, 256, 0, stream>>>(sc, memp, ps, ao, msk);
    k_na<2><<<nag, 128, 0, stream>>>(x, ao, msk, nullptr, nullptr, tU, tV);
    k_fin2<<<1, 64, 0, stream>>>(tU, tV, scu, scv);
    k_na<3><<<nag, 128, 0, stream>>>(x, ao, msk, scu, scv, tU, nullptr);
    k_fin1<<<1, 64, 0, stream>>>(tU, scw);
    k_a2<<<41472, 256, 0, stream>>>(x, ao, msk, scu, scv, scw);
  }

  k_o0<<<41472, 256, 0, stream>>>(x, out);
  k_o1<<<41472, 256, 0, stream>>>(x, out + (size_t)LL * BB * DD);
}